// Round 14
// baseline (134.090 us; speedup 1.0000x reference)
//
#include <hip/hip_runtime.h>
#include <hip/hip_bf16.h>
#include <math.h>

#define B 128
#define C 2048
#define N 196
#define K 112
#define KB 113
#define MROWS 128
#define XWROW 113
#define NCLS 200
#define CKC (C * K)
#define NT 7            // 7 col-tiles of 32
#define MAIN_BLKS 896   // 128 * 7
#define PQ_BLKS 1400    // 22400 wids / 16
#define BKP 72          // XT row stride in u16 (144B)
#define XADV (64 * N)

#define OUT1_OFF 2834944
#define OUT2_OFF 2849280

typedef __attribute__((ext_vector_type(8))) short bf16x8;
typedef __attribute__((ext_vector_type(4))) float f32x4;

__device__ inline unsigned cvtpk(float a, float b) {
    union { __hip_bfloat162 h; unsigned u; } c;
    c.h.x = __float2bfloat16(a);
    c.h.y = __float2bfloat16(b);
    return c.u;
}
__device__ inline const float* row_src(int row, const float* concepts,
                                       const float* background, const float* wcfc) {
    if (row < K) return concepts + (size_t)row * C;
    if (row == K) return background;
    if (row == XWROW) return wcfc;
    return nullptr;
}

// ---------------------------------------------------------------------------
__global__ __launch_bounds__(256)
void asq_kernel(const float* __restrict__ concepts, const float* __restrict__ background,
                const float* __restrict__ wcfc, float* __restrict__ asq) {
    const int row = blockIdx.x;
    const int tid = threadIdx.x;
    const float* src = row_src(row, concepts, background, wcfc);
    float local = 0.f;
    if (src) for (int i = tid; i < C; i += 256) { float v = src[i]; local += v * v; }
    for (int off = 32; off; off >>= 1) local += __shfl_down(local, off);
    __shared__ float red[4];
    if ((tid & 63) == 0) red[tid >> 6] = local;
    __syncthreads();
    if (tid == 0) asq[row] = red[0] + red[1] + red[2] + red[3];
}

// ---------------------------------------------------------------------------
// pack: Afrag[kwg 0..63][f 0..7][lane][8 bf16]; lane l of (kwg,f) holds
//       A[16f+(l&15)][32kwg+8(l>>4)+j]
// ---------------------------------------------------------------------------
__global__ __launch_bounds__(64)
void pack_kernel(const float* __restrict__ concepts, const float* __restrict__ background,
                 const float* __restrict__ wcfc, unsigned short* __restrict__ Afrag) {
    const int f = blockIdx.x;
    const int kwg = blockIdx.y;
    const int l = threadIdx.x;
    const int row = 16 * f + (l & 15);
    const int kb = 32 * kwg + 8 * (l >> 4);
    const float* src = row_src(row, concepts, background, wcfc);
    unsigned o[4] = {0u, 0u, 0u, 0u};
    if (src) {
        const float4 f0 = *reinterpret_cast<const float4*>(src + kb);
        const float4 f1 = *reinterpret_cast<const float4*>(src + kb + 4);
        o[0] = cvtpk(f0.x, f0.y); o[1] = cvtpk(f0.z, f0.w);
        o[2] = cvtpk(f1.x, f1.y); o[3] = cvtpk(f1.z, f1.w);
    }
    *reinterpret_cast<uint4*>(Afrag + (((size_t)kwg * 8 + f) * 64 + l) * 8) =
        make_uint4(o[0], o[1], o[2], o[3]);
}

// ---------------------------------------------------------------------------
// fused_kernel (256 thr, 4 waves):
//  blkid < MAIN_BLKS : dots[128][32] = A @ x_b[:,32cols]; wave w owns rows
//    32w..32w+31. Double-buffered XT[32][72]; one lgkm-barrier per K-step;
//    2-deep pure-load prefetch (15x2 loop + 2-iter epilogue — 32 staged total);
//    small LDS + small acc -> 4 blocks/CU.
//  else : pq body, 16 wids per block (4/wave).
// ---------------------------------------------------------------------------
__global__ __launch_bounds__(256, 4)
void fused_kernel(const float* __restrict__ x,
                  const unsigned short* __restrict__ Afrag,
                  const float* __restrict__ asq_g,
                  float* __restrict__ out0,
                  float* __restrict__ lpart,
                  const float* __restrict__ wlfc,
                  const float* __restrict__ concepts,
                  const float* __restrict__ modulation,
                  float* __restrict__ Rm, float* __restrict__ Qs) {
    __shared__ __align__(16) char smem[21504];
    const int tid = threadIdx.x;
    const int lane = tid & 63;
    const int w = tid >> 6;
    const int blkid = blockIdx.x;

    if (blkid < MAIN_BLKS) {
        unsigned short* XT0 = (unsigned short*)smem;            // [32][72] u16
        unsigned short* XT1 = (unsigned short*)(smem + 4608);
        float* dotsL = (float*)smem;                            // overlay [128][34]
        float* xsqp  = (float*)(smem + 17920);                  // [8][32]
        float* asq_s = (float*)(smem + 18944);                  // [128]
        float* pm    = (float*)(smem + 19456);                  // [8][32]
        float* ps    = (float*)(smem + 20480);                  // [8][32]

        const int b = blkid / NT;
        const int nt = blkid - b * NT;
        const int n0 = nt * 32;
        const int lo = lane & 15, hi = lane >> 4;

        // staging: thread covers k-chunk (tid>>5) of 8 ks, single col (tid&31)
        const int kc = tid >> 5;
        const int pr = tid & 31;
        const int ns = n0 + pr;
        const unsigned mm = (ns < N) ? 0xFFFFFFFFu : 0u;
        const int nsc = (ns < N) ? ns : (N - 1);
        const float* xstage = x + (size_t)b * C * N + (size_t)kc * 8 * N + nsc;

        f32x4 acc[2][2];
#pragma unroll
        for (int i = 0; i < 2; ++i) {
            acc[i][0] = (f32x4){0.f, 0.f, 0.f, 0.f};
            acc[i][1] = (f32x4){0.f, 0.f, 0.f, 0.f};
        }
        float xs = 0.f;

#define STAGE_LOAD(R) do {                                                      \
        (R##0) = xstage[(size_t)0 * N];                                         \
        (R##1) = xstage[(size_t)1 * N];                                         \
        (R##2) = xstage[(size_t)2 * N];                                         \
        (R##3) = xstage[(size_t)3 * N];                                         \
        (R##4) = xstage[(size_t)4 * N];                                         \
        (R##5) = xstage[(size_t)5 * N];                                         \
        (R##6) = xstage[(size_t)6 * N];                                         \
        (R##7) = xstage[(size_t)7 * N];                                         \
        xstage += XADV;                                                         \
    } while (0)

#define LOAD_A(A, it) do {                                                      \
        _Pragma("unroll")                                                       \
        for (int rt_ = 0; rt_ < 2; ++rt_)                                       \
            _Pragma("unroll")                                                   \
            for (int kw_ = 0; kw_ < 2; ++kw_)                                   \
                A[rt_ * 2 + kw_] = *reinterpret_cast<const bf16x8*>(            \
                    Afrag + ((((size_t)(2 * (it) + kw_)) * 8 + (2 * w + rt_))   \
                             * 64 + lane) * 8);                                 \
    } while (0)

#define PACK_WRITE(R, XTB) do {                                                 \
        xs += (R##0) * (R##0) + (R##1) * (R##1) + (R##2) * (R##2)               \
            + (R##3) * (R##3) + (R##4) * (R##4) + (R##5) * (R##5)               \
            + (R##6) * (R##6) + (R##7) * (R##7);                                \
        unsigned u0_ = cvtpk((R##0), (R##1)) & mm;                              \
        unsigned u1_ = cvtpk((R##2), (R##3)) & mm;                              \
        unsigned u2_ = cvtpk((R##4), (R##5)) & mm;                              \
        unsigned u3_ = cvtpk((R##6), (R##7)) & mm;                              \
        *reinterpret_cast<uint4*>(XTB + (size_t)pr * BKP + kc * 8) =            \
            make_uint4(u0_, u1_, u2_, u3_);                                     \
    } while (0)

#define MFMA_PHASE(A, XTB) do {                                                 \
        _Pragma("unroll")                                                       \
        for (int kw_ = 0; kw_ < 2; ++kw_) {                                     \
            _Pragma("unroll")                                                   \
            for (int ct_ = 0; ct_ < 2; ++ct_) {                                 \
                const bf16x8 bv_ = *reinterpret_cast<const bf16x8*>(            \
                    XTB + (size_t)(ct_ * 16 + lo) * BKP + kw_ * 32 + hi * 8);   \
                acc[0][ct_] = __builtin_amdgcn_mfma_f32_16x16x32_bf16(          \
                    A[kw_], bv_, acc[0][ct_], 0, 0, 0);                         \
                acc[1][ct_] = __builtin_amdgcn_mfma_f32_16x16x32_bf16(          \
                    A[2 + kw_], bv_, acc[1][ct_], 0, 0, 0);                     \
            }                                                                   \
        }                                                                       \
    } while (0)

#define BAR() do {                                                              \
        asm volatile("s_waitcnt lgkmcnt(0)" ::: "memory");                      \
        __builtin_amdgcn_s_barrier();                                           \
        __builtin_amdgcn_sched_barrier(0);                                      \
    } while (0)

        float rA0, rA1, rA2, rA3, rA4, rA5, rA6, rA7;
        float rB0, rB1, rB2, rB3, rB4, rB5, rB6, rB7;
        bf16x8 aA[4], aB[4];

        STAGE_LOAD(rA); STAGE_LOAD(rB);        // iters 0,1
        LOAD_A(aA, 0); LOAD_A(aB, 1);

        // 15 x 2 iters: consume 0..29, stage 2..31 (32 staged total)
        for (int itp = 0; itp < 15; ++itp) {
            const int j0 = 2 * itp;
            PACK_WRITE(rA, XT0); STAGE_LOAD(rA); BAR();
            MFMA_PHASE(aA, XT0); LOAD_A(aA, j0 + 2);
            PACK_WRITE(rB, XT1); STAGE_LOAD(rB); BAR();
            MFMA_PHASE(aB, XT1); LOAD_A(aB, j0 + 3);
        }
        // iters 30, 31 (rA=30, rB=31, aA=A30, aB=A31)
        PACK_WRITE(rA, XT0); BAR(); MFMA_PHASE(aA, XT0);
        PACK_WRITE(rB, XT1); BAR(); MFMA_PHASE(aB, XT1);

        __syncthreads();                           // XT -> dotsL overlay
        // C/D map: col=lane&15, row = 16*(2w+rt)+4*hi+rr (m89-verified)
#pragma unroll
        for (int rt = 0; rt < 2; ++rt)
#pragma unroll
            for (int ct = 0; ct < 2; ++ct)
#pragma unroll
                for (int rr = 0; rr < 4; ++rr)
                    dotsL[(size_t)(16 * (2 * w + rt) + 4 * hi + rr) * 34 +
                          ct * 16 + lo] = acc[rt][ct][rr];
        xsqp[kc * 32 + pr] = xs;
        if (tid < MROWS) asq_s[tid] = asq_g[tid];
        __syncthreads();

        // softmax: 8 groups of 32 threads; group g handles rows 15g..15g+14
        const int g8 = tid >> 5;
        const int j = tid & 31;
        float xsq = 0.f;
#pragma unroll
        for (int c = 0; c < 8; ++c) xsq += xsqp[c * 32 + j];
        const int rbeg = 15 * g8;
        const int rend = (rbeg + 15 < KB) ? rbeg + 15 : KB;

        float m = -3.4e38f;
        for (int r = rbeg; r < rend; ++r) {
            const float d2 = asq_s[r] + xsq - 2.f * dotsL[(size_t)r * 34 + j];
            const float L = -sqrtf(fmaxf(d2, 0.f));
            dotsL[(size_t)r * 34 + j] = L;
            m = fmaxf(m, L);
        }
        pm[g8 * 32 + j] = m;
        __syncthreads();
        float M = pm[j];
#pragma unroll
        for (int c = 1; c < 8; ++c) M = fmaxf(M, pm[c * 32 + j]);
        float s = 0.f;
        for (int r = rbeg; r < rend; ++r) s += __expf(dotsL[(size_t)r * 34 + j] - M);
        ps[g8 * 32 + j] = s;
        __syncthreads();
        float S = ps[j];
#pragma unroll
        for (int c = 1; c < 8; ++c) S += ps[c * 32 + j];
        const float invS = 1.f / S;
        const float xw = dotsL[(size_t)XWROW * 34 + j];   // raw dot (0 for pad cols)

        const bool jv = (n0 + j) < N;
        float* o0 = out0 + (size_t)b * KB * N + n0 + j;
        for (int r = rbeg; r < rend; ++r) {
            const float a = __expf(dotsL[(size_t)r * 34 + j] - M) * invS;
            if (jv) o0[(size_t)r * N] = a;
            if (r < K) {
                float pv = a * xw;                 // xw==0 for pad cols
                pv += __shfl_xor(pv, 1);
                pv += __shfl_xor(pv, 2);
                pv += __shfl_xor(pv, 4);
                pv += __shfl_xor(pv, 8);
                pv += __shfl_xor(pv, 16);
                if (j == 0) lpart[((size_t)b * NT + nt) * K + r] = pv;
            }
        }
    } else {
        // ---------------- pq body: 16 wids per block (4 per wave) -----------
        const int wb = (blkid - MAIN_BLKS) * 16 + w * 4;
#pragma unroll
        for (int q = 0; q < 4; ++q) {
            const int wid = wb + q;
            const int o = wid / K;
            const int k = wid % K;
            const float4* wp = reinterpret_cast<const float4*>(wlfc + (size_t)o * CKC + (size_t)k * C);
            const float4* cp = reinterpret_cast<const float4*>(concepts + (size_t)k * C);
            const float4* mp = reinterpret_cast<const float4*>(modulation);
            float s1 = 0.f, s2 = 0.f;
#pragma unroll
            for (int it = 0; it < 8; ++it) {
                const int idx = it * 64 + lane;
                const float4 w4 = wp[idx];
                const float4 c4 = cp[idx];
                const float4 m4 = mp[idx];
                s1 += w4.x * c4.x + w4.y * c4.y + w4.z * c4.z + w4.w * c4.w;
                s2 += w4.x * m4.x + w4.y * m4.y + w4.z * m4.z + w4.w * m4.w;
            }
            for (int off = 32; off; off >>= 1) {
                s1 += __shfl_down(s1, off);
                s2 += __shfl_down(s2, off);
            }
            if (lane == 0) { Rm[wid] = s1 - s2; Qs[wid] = s2; }
        }
    }
}

// ---------------------------------------------------------------------------
__global__ __launch_bounds__(256)
void final_kernel(const float* __restrict__ lpart, const float* __restrict__ bcfc,
                  const float* __restrict__ Rm, const float* __restrict__ Qs,
                  const float* __restrict__ blfc,
                  float* __restrict__ out1, float* __restrict__ out2) {
    const int b = blockIdx.x;
    const int tid = threadIdx.x;
    __shared__ float g_s[K];
    if (tid < K) {
        const float* lp = lpart + (size_t)b * NT * K + tid;
        float v = bcfc[0];
#pragma unroll
        for (int t = 0; t < NT; ++t) v += lp[(size_t)t * K];
        const float g = 1.f / (1.f + __expf(-v));
        out1[b * K + tid] = g;
        g_s[tid] = g;
    }
    __syncthreads();
    if (tid < NCLS) {
        float acc = blfc[tid];
        const float* rp = Rm + (size_t)tid * K;
        const float* qp = Qs + (size_t)tid * K;
        for (int k = 0; k < K; ++k) acc = fmaf(g_s[k], rp[k], acc) + qp[k];
        out2[b * NCLS + tid] = acc;
    }
}

extern "C" void kernel_launch(void* const* d_in, const int* in_sizes, int n_in,
                              void* d_out, int out_size, void* d_ws, size_t ws_size,
                              hipStream_t stream) {
    const float* x          = (const float*)d_in[0];
    const float* concepts   = (const float*)d_in[1];
    const float* modulation = (const float*)d_in[2];
    const float* background = (const float*)d_in[3];
    const float* wcfc       = (const float*)d_in[4];
    const float* bcfc       = (const float*)d_in[5];
    const float* wlfc       = (const float*)d_in[6];
    const float* blfc       = (const float*)d_in[7];

    float* out  = (float*)d_out;
    float* out0 = out;
    float* out1 = out + OUT1_OFF;
    float* out2 = out + OUT2_OFF;

    float* ws    = (float*)d_ws;
    float* asq   = ws;                               // 128
    float* lpart = asq + MROWS;                      // 128*7*112
    float* Rm    = lpart + (size_t)B * NT * K;       // 22400
    float* Qs    = Rm + NCLS * K;                    // 22400
    unsigned short* Afrag = (unsigned short*)(Qs + NCLS * K);  // 512KB

    asq_kernel<<<MROWS, 256, 0, stream>>>(concepts, background, wcfc, asq);
    pack_kernel<<<dim3(8, 64), 64, 0, stream>>>(concepts, background, wcfc, Afrag);
    fused_kernel<<<MAIN_BLKS + PQ_BLKS, 256, 0, stream>>>(
        x, Afrag, asq, out0, lpart, wlfc, concepts, modulation, Rm, Qs);
    final_kernel<<<B, 256, 0, stream>>>(lpart, bcfc, Rm, Qs, blfc, out1, out2);
}

// Round 15
// 128.922 us; speedup vs baseline: 1.0401x; 1.0401x over previous
//
#include <hip/hip_runtime.h>
#include <hip/hip_bf16.h>
#include <math.h>

#define B 128
#define C 2048
#define N 196
#define K 112
#define KB 113
#define MROWS 128
#define XWROW 113
#define NCLS 200
#define CKC (C * K)
#define NT 7            // 7 col-tiles of 32
#define MAIN_BLKS 896   // 128 * 7
#define PQ_BLKS 1400    // 22400 wids / 16
#define BKP 72          // XT row stride in u16 (144B)
#define XADV (64 * N)

#define OUT1_OFF 2834944
#define OUT2_OFF 2849280

typedef __attribute__((ext_vector_type(8))) short bf16x8;
typedef __attribute__((ext_vector_type(4))) float f32x4;

__device__ inline unsigned cvtpk(float a, float b) {
    union { __hip_bfloat162 h; unsigned u; } c;
    c.h.x = __float2bfloat16(a);
    c.h.y = __float2bfloat16(b);
    return c.u;
}
__device__ inline const float* row_src(int row, const float* concepts,
                                       const float* background, const float* wcfc) {
    if (row < K) return concepts + (size_t)row * C;
    if (row == K) return background;
    if (row == XWROW) return wcfc;
    return nullptr;
}

// ---------------------------------------------------------------------------
__global__ __launch_bounds__(256)
void asq_kernel(const float* __restrict__ concepts, const float* __restrict__ background,
                const float* __restrict__ wcfc, float* __restrict__ asq) {
    const int row = blockIdx.x;
    const int tid = threadIdx.x;
    const float* src = row_src(row, concepts, background, wcfc);
    float local = 0.f;
    if (src) for (int i = tid; i < C; i += 256) { float v = src[i]; local += v * v; }
    for (int off = 32; off; off >>= 1) local += __shfl_down(local, off);
    __shared__ float red[4];
    if ((tid & 63) == 0) red[tid >> 6] = local;
    __syncthreads();
    if (tid == 0) asq[row] = red[0] + red[1] + red[2] + red[3];
}

// ---------------------------------------------------------------------------
// pack: Afrag[kwg 0..63][f 0..7][lane][8 bf16]; lane l of (kwg,f) holds
//       A[16f+(l&15)][32kwg+8(l>>4)+j]
// ---------------------------------------------------------------------------
__global__ __launch_bounds__(64)
void pack_kernel(const float* __restrict__ concepts, const float* __restrict__ background,
                 const float* __restrict__ wcfc, unsigned short* __restrict__ Afrag) {
    const int f = blockIdx.x;
    const int kwg = blockIdx.y;
    const int l = threadIdx.x;
    const int row = 16 * f + (l & 15);
    const int kb = 32 * kwg + 8 * (l >> 4);
    const float* src = row_src(row, concepts, background, wcfc);
    unsigned o[4] = {0u, 0u, 0u, 0u};
    if (src) {
        const float4 f0 = *reinterpret_cast<const float4*>(src + kb);
        const float4 f1 = *reinterpret_cast<const float4*>(src + kb + 4);
        o[0] = cvtpk(f0.x, f0.y); o[1] = cvtpk(f0.z, f0.w);
        o[2] = cvtpk(f1.x, f1.y); o[3] = cvtpk(f1.z, f1.w);
    }
    *reinterpret_cast<uint4*>(Afrag + (((size_t)kwg * 8 + f) * 64 + l) * 8) =
        make_uint4(o[0], o[1], o[2], o[3]);
}

// ---------------------------------------------------------------------------
// fused_kernel (256 thr, 4 waves):
//  blkid < MAIN_BLKS : dots[128][32] = A @ x_b[:,32cols].
//    XCD-aware remap: all 7 tiles of an image land on ONE XCD (bid%8 = XCD)
//    so the 1.6MB x-slab is pulled through L3 once and served from L2.
//  else : pq body, 16 wids per block (4/wave).
// ---------------------------------------------------------------------------
__global__ __launch_bounds__(256, 4)
void fused_kernel(const float* __restrict__ x,
                  const unsigned short* __restrict__ Afrag,
                  const float* __restrict__ asq_g,
                  float* __restrict__ out0,
                  float* __restrict__ lpart,
                  const float* __restrict__ wlfc,
                  const float* __restrict__ concepts,
                  const float* __restrict__ modulation,
                  float* __restrict__ Rm, float* __restrict__ Qs) {
    __shared__ __align__(16) char smem[21504];
    const int tid = threadIdx.x;
    const int lane = tid & 63;
    const int w = tid >> 6;
    const int blkid = blockIdx.x;

    if (blkid < MAIN_BLKS) {
        unsigned short* XT0 = (unsigned short*)smem;            // [32][72] u16
        unsigned short* XT1 = (unsigned short*)(smem + 4608);
        float* dotsL = (float*)smem;                            // overlay [128][34]
        float* xsqp  = (float*)(smem + 17920);                  // [8][32]
        float* asq_s = (float*)(smem + 18944);                  // [128]
        float* pm    = (float*)(smem + 19456);                  // [8][32]
        float* ps    = (float*)(smem + 20480);                  // [8][32]

        // XCD-aware remap: bid%8 selects XCD (HW round-robin); give each XCD
        // 16 whole images (16 img x 7 tiles = 112 = 896/8 blocks per XCD).
        const int xcd = blkid & 7;
        const int jj = blkid >> 3;          // 0..111
        const int b = xcd + 8 * (jj / NT);  // image
        const int nt = jj - NT * (jj / NT); // tile within image
        const int n0 = nt * 32;
        const int lo = lane & 15, hi = lane >> 4;

        // staging: thread covers k-chunk (tid>>5) of 8 ks, single col (tid&31)
        const int kc = tid >> 5;
        const int pr = tid & 31;
        const int ns = n0 + pr;
        const unsigned mm = (ns < N) ? 0xFFFFFFFFu : 0u;
        const int nsc = (ns < N) ? ns : (N - 1);
        const float* xstage = x + (size_t)b * C * N + (size_t)kc * 8 * N + nsc;

        f32x4 acc[2][2];
#pragma unroll
        for (int i = 0; i < 2; ++i) {
            acc[i][0] = (f32x4){0.f, 0.f, 0.f, 0.f};
            acc[i][1] = (f32x4){0.f, 0.f, 0.f, 0.f};
        }
        float xs = 0.f;

#define STAGE_LOAD(R) do {                                                      \
        (R##0) = xstage[(size_t)0 * N];                                         \
        (R##1) = xstage[(size_t)1 * N];                                         \
        (R##2) = xstage[(size_t)2 * N];                                         \
        (R##3) = xstage[(size_t)3 * N];                                         \
        (R##4) = xstage[(size_t)4 * N];                                         \
        (R##5) = xstage[(size_t)5 * N];                                         \
        (R##6) = xstage[(size_t)6 * N];                                         \
        (R##7) = xstage[(size_t)7 * N];                                         \
        xstage += XADV;                                                         \
    } while (0)

#define LOAD_A(A, it) do {                                                      \
        _Pragma("unroll")                                                       \
        for (int rt_ = 0; rt_ < 2; ++rt_)                                       \
            _Pragma("unroll")                                                   \
            for (int kw_ = 0; kw_ < 2; ++kw_)                                   \
                A[rt_ * 2 + kw_] = *reinterpret_cast<const bf16x8*>(            \
                    Afrag + ((((size_t)(2 * (it) + kw_)) * 8 + (2 * w + rt_))   \
                             * 64 + lane) * 8);                                 \
    } while (0)

#define PACK_WRITE(R, XTB) do {                                                 \
        xs += (R##0) * (R##0) + (R##1) * (R##1) + (R##2) * (R##2)               \
            + (R##3) * (R##3) + (R##4) * (R##4) + (R##5) * (R##5)               \
            + (R##6) * (R##6) + (R##7) * (R##7);                                \
        unsigned u0_ = cvtpk((R##0), (R##1)) & mm;                              \
        unsigned u1_ = cvtpk((R##2), (R##3)) & mm;                              \
        unsigned u2_ = cvtpk((R##4), (R##5)) & mm;                              \
        unsigned u3_ = cvtpk((R##6), (R##7)) & mm;                              \
        *reinterpret_cast<uint4*>(XTB + (size_t)pr * BKP + kc * 8) =            \
            make_uint4(u0_, u1_, u2_, u3_);                                     \
    } while (0)

#define MFMA_PHASE(A, XTB) do {                                                 \
        _Pragma("unroll")                                                       \
        for (int kw_ = 0; kw_ < 2; ++kw_) {                                     \
            _Pragma("unroll")                                                   \
            for (int ct_ = 0; ct_ < 2; ++ct_) {                                 \
                const bf16x8 bv_ = *reinterpret_cast<const bf16x8*>(            \
                    XTB + (size_t)(ct_ * 16 + lo) * BKP + kw_ * 32 + hi * 8);   \
                acc[0][ct_] = __builtin_amdgcn_mfma_f32_16x16x32_bf16(          \
                    A[kw_], bv_, acc[0][ct_], 0, 0, 0);                         \
                acc[1][ct_] = __builtin_amdgcn_mfma_f32_16x16x32_bf16(          \
                    A[2 + kw_], bv_, acc[1][ct_], 0, 0, 0);                     \
            }                                                                   \
        }                                                                       \
    } while (0)

#define BAR() do {                                                              \
        asm volatile("s_waitcnt lgkmcnt(0)" ::: "memory");                      \
        __builtin_amdgcn_s_barrier();                                           \
        __builtin_amdgcn_sched_barrier(0);                                      \
    } while (0)

        float rA0, rA1, rA2, rA3, rA4, rA5, rA6, rA7;
        float rB0, rB1, rB2, rB3, rB4, rB5, rB6, rB7;
        bf16x8 aA[4], aB[4];

        STAGE_LOAD(rA); STAGE_LOAD(rB);        // iters 0,1
        LOAD_A(aA, 0); LOAD_A(aB, 1);

        // 15 x 2 iters: consume 0..29, stage 2..31 (32 staged total)
        for (int itp = 0; itp < 15; ++itp) {
            const int j0 = 2 * itp;
            PACK_WRITE(rA, XT0); STAGE_LOAD(rA); BAR();
            MFMA_PHASE(aA, XT0); LOAD_A(aA, j0 + 2);
            PACK_WRITE(rB, XT1); STAGE_LOAD(rB); BAR();
            MFMA_PHASE(aB, XT1); LOAD_A(aB, j0 + 3);
        }
        // iters 30, 31 (rA=30, rB=31, aA=A30, aB=A31)
        PACK_WRITE(rA, XT0); BAR(); MFMA_PHASE(aA, XT0);
        PACK_WRITE(rB, XT1); BAR(); MFMA_PHASE(aB, XT1);

        __syncthreads();                           // XT -> dotsL overlay
        // C/D map: col=lane&15, row = 16*(2w+rt)+4*hi+rr (m89-verified)
#pragma unroll
        for (int rt = 0; rt < 2; ++rt)
#pragma unroll
            for (int ct = 0; ct < 2; ++ct)
#pragma unroll
                for (int rr = 0; rr < 4; ++rr)
                    dotsL[(size_t)(16 * (2 * w + rt) + 4 * hi + rr) * 34 +
                          ct * 16 + lo] = acc[rt][ct][rr];
        xsqp[kc * 32 + pr] = xs;
        if (tid < MROWS) asq_s[tid] = asq_g[tid];
        __syncthreads();

        // softmax: 8 groups of 32 threads; group g handles rows 15g..15g+14
        const int g8 = tid >> 5;
        const int j = tid & 31;
        float xsq = 0.f;
#pragma unroll
        for (int c = 0; c < 8; ++c) xsq += xsqp[c * 32 + j];
        const int rbeg = 15 * g8;
        const int rend = (rbeg + 15 < KB) ? rbeg + 15 : KB;

        float m = -3.4e38f;
        for (int r = rbeg; r < rend; ++r) {
            const float d2 = asq_s[r] + xsq - 2.f * dotsL[(size_t)r * 34 + j];
            const float L = -sqrtf(fmaxf(d2, 0.f));
            dotsL[(size_t)r * 34 + j] = L;
            m = fmaxf(m, L);
        }
        pm[g8 * 32 + j] = m;
        __syncthreads();
        float M = pm[j];
#pragma unroll
        for (int c = 1; c < 8; ++c) M = fmaxf(M, pm[c * 32 + j]);
        float s = 0.f;
        for (int r = rbeg; r < rend; ++r) s += __expf(dotsL[(size_t)r * 34 + j] - M);
        ps[g8 * 32 + j] = s;
        __syncthreads();
        float S = ps[j];
#pragma unroll
        for (int c = 1; c < 8; ++c) S += ps[c * 32 + j];
        const float invS = 1.f / S;
        const float xw = dotsL[(size_t)XWROW * 34 + j];   // raw dot (0 for pad cols)

        const bool jv = (n0 + j) < N;
        float* o0 = out0 + (size_t)b * KB * N + n0 + j;
        for (int r = rbeg; r < rend; ++r) {
            const float a = __expf(dotsL[(size_t)r * 34 + j] - M) * invS;
            if (jv) o0[(size_t)r * N] = a;
            if (r < K) {
                float pv = a * xw;                 // xw==0 for pad cols
                pv += __shfl_xor(pv, 1);
                pv += __shfl_xor(pv, 2);
                pv += __shfl_xor(pv, 4);
                pv += __shfl_xor(pv, 8);
                pv += __shfl_xor(pv, 16);
                if (j == 0) lpart[((size_t)b * NT + nt) * K + r] = pv;
            }
        }
    } else {
        // ---------------- pq body: 16 wids per block (4 per wave) -----------
        const int wb = (blkid - MAIN_BLKS) * 16 + w * 4;
#pragma unroll
        for (int q = 0; q < 4; ++q) {
            const int wid = wb + q;
            const int o = wid / K;
            const int k = wid % K;
            const float4* wp = reinterpret_cast<const float4*>(wlfc + (size_t)o * CKC + (size_t)k * C);
            const float4* cp = reinterpret_cast<const float4*>(concepts + (size_t)k * C);
            const float4* mp = reinterpret_cast<const float4*>(modulation);
            float s1 = 0.f, s2 = 0.f;
#pragma unroll
            for (int it = 0; it < 8; ++it) {
                const int idx = it * 64 + lane;
                const float4 w4 = wp[idx];
                const float4 c4 = cp[idx];
                const float4 m4 = mp[idx];
                s1 += w4.x * c4.x + w4.y * c4.y + w4.z * c4.z + w4.w * c4.w;
                s2 += w4.x * m4.x + w4.y * m4.y + w4.z * m4.z + w4.w * m4.w;
            }
            for (int off = 32; off; off >>= 1) {
                s1 += __shfl_down(s1, off);
                s2 += __shfl_down(s2, off);
            }
            if (lane == 0) { Rm[wid] = s1 - s2; Qs[wid] = s2; }
        }
    }
}

// ---------------------------------------------------------------------------
__global__ __launch_bounds__(256)
void final_kernel(const float* __restrict__ lpart, const float* __restrict__ bcfc,
                  const float* __restrict__ Rm, const float* __restrict__ Qs,
                  const float* __restrict__ blfc,
                  float* __restrict__ out1, float* __restrict__ out2) {
    const int b = blockIdx.x;
    const int tid = threadIdx.x;
    __shared__ float g_s[K];
    if (tid < K) {
        const float* lp = lpart + (size_t)b * NT * K + tid;
        float v = bcfc[0];
#pragma unroll
        for (int t = 0; t < NT; ++t) v += lp[(size_t)t * K];
        const float g = 1.f / (1.f + __expf(-v));
        out1[b * K + tid] = g;
        g_s[tid] = g;
    }
    __syncthreads();
    if (tid < NCLS) {
        float acc = blfc[tid];
        const float* rp = Rm + (size_t)tid * K;
        const float* qp = Qs + (size_t)tid * K;
        for (int k = 0; k < K; ++k) acc = fmaf(g_s[k], rp[k], acc) + qp[k];
        out2[b * NCLS + tid] = acc;
    }
}

extern "C" void kernel_launch(void* const* d_in, const int* in_sizes, int n_in,
                              void* d_out, int out_size, void* d_ws, size_t ws_size,
                              hipStream_t stream) {
    const float* x          = (const float*)d_in[0];
    const float* concepts   = (const float*)d_in[1];
    const float* modulation = (const float*)d_in[2];
    const float* background = (const float*)d_in[3];
    const float* wcfc       = (const float*)d_in[4];
    const float* bcfc       = (const float*)d_in[5];
    const float* wlfc       = (const float*)d_in[6];
    const float* blfc       = (const float*)d_in[7];

    float* out  = (float*)d_out;
    float* out0 = out;
    float* out1 = out + OUT1_OFF;
    float* out2 = out + OUT2_OFF;

    float* ws    = (float*)d_ws;
    float* asq   = ws;                               // 128
    float* lpart = asq + MROWS;                      // 128*7*112
    float* Rm    = lpart + (size_t)B * NT * K;       // 22400
    float* Qs    = Rm + NCLS * K;                    // 22400
    unsigned short* Afrag = (unsigned short*)(Qs + NCLS * K);  // 512KB

    asq_kernel<<<MROWS, 256, 0, stream>>>(concepts, background, wcfc, asq);
    pack_kernel<<<dim3(8, 64), 64, 0, stream>>>(concepts, background, wcfc, Afrag);
    fused_kernel<<<MAIN_BLKS + PQ_BLKS, 256, 0, stream>>>(
        x, Afrag, asq, out0, lpart, wlfc, concepts, modulation, Rm, Qs);
    final_kernel<<<B, 256, 0, stream>>>(lpart, bcfc, Rm, Qs, blfc, out1, out2);
}

// Round 16
// 121.270 us; speedup vs baseline: 1.1057x; 1.0631x over previous
//
#include <hip/hip_runtime.h>
#include <hip/hip_bf16.h>
#include <math.h>

#define B 128
#define C 2048
#define N 196
#define K 112
#define KB 113
#define MROWS 128
#define XWROW 113
#define NCLS 200
#define CKC (C * K)
#define MAIN_BLKS 128
#define PQ_BLKS 700        // 22400 wids / 32
#define XSTEP 25088        // 32 k-rows * 196 cols * 4B
#define IMGB (C * N * 4)   // 1605632

#define OUT1_OFF 2834944
#define OUT2_OFF 2849280

typedef __attribute__((ext_vector_type(8))) short bf16x8;
typedef __attribute__((ext_vector_type(4))) float f32x4;

__device__ inline unsigned cvtpk(float a, float b) {
    union { __hip_bfloat162 h; unsigned u; } c;
    c.h.x = __float2bfloat16(a);
    c.h.y = __float2bfloat16(b);
    return c.u;
}
__device__ inline const float* row_src(int row, const float* concepts,
                                       const float* background, const float* wcfc) {
    if (row < K) return concepts + (size_t)row * C;
    if (row == K) return background;
    if (row == XWROW) return wcfc;
    return nullptr;
}
// global->LDS DMA: per-lane global addr, wave-uniform LDS base (+lane*size by HW)
__device__ __forceinline__ void gl16(const void* g, void* l) {
    __builtin_amdgcn_global_load_lds(
        (const __attribute__((address_space(1))) unsigned*)g,
        (__attribute__((address_space(3))) unsigned*)l, 16, 0, 0);
}
__device__ __forceinline__ void gl4(const void* g, void* l) {
    __builtin_amdgcn_global_load_lds(
        (const __attribute__((address_space(1))) unsigned*)g,
        (__attribute__((address_space(3))) unsigned*)l, 4, 0, 0);
}

// ---------------------------------------------------------------------------
__global__ __launch_bounds__(256)
void asq_kernel(const float* __restrict__ concepts, const float* __restrict__ background,
                const float* __restrict__ wcfc, float* __restrict__ asq) {
    const int row = blockIdx.x;
    const int tid = threadIdx.x;
    const float* src = row_src(row, concepts, background, wcfc);
    float local = 0.f;
    if (src) for (int i = tid; i < C; i += 256) { float v = src[i]; local += v * v; }
    for (int off = 32; off; off >>= 1) local += __shfl_down(local, off);
    __shared__ float red[4];
    if ((tid & 63) == 0) red[tid >> 6] = local;
    __syncthreads();
    if (tid == 0) asq[row] = red[0] + red[1] + red[2] + red[3];
}

// ---------------------------------------------------------------------------
// pack: Afrag[kwg 0..63][f 0..7][lane][8 bf16]; lane l of (kwg,f) holds
//       A[16f+(l&15)][32kwg+8(l>>4)+j]  (8KB per kwg — DMA chunk = 1KB per f)
// ---------------------------------------------------------------------------
__global__ __launch_bounds__(64)
void pack_kernel(const float* __restrict__ concepts, const float* __restrict__ background,
                 const float* __restrict__ wcfc, unsigned short* __restrict__ Afrag) {
    const int f = blockIdx.x;
    const int kwg = blockIdx.y;
    const int l = threadIdx.x;
    const int row = 16 * f + (l & 15);
    const int kb = 32 * kwg + 8 * (l >> 4);
    const float* src = row_src(row, concepts, background, wcfc);
    unsigned o[4] = {0u, 0u, 0u, 0u};
    if (src) {
        const float4 f0 = *reinterpret_cast<const float4*>(src + kb);
        const float4 f1 = *reinterpret_cast<const float4*>(src + kb + 4);
        o[0] = cvtpk(f0.x, f0.y); o[1] = cvtpk(f0.z, f0.w);
        o[2] = cvtpk(f1.x, f1.y); o[3] = cvtpk(f1.z, f1.w);
    }
    *reinterpret_cast<uint4*>(Afrag + (((size_t)kwg * 8 + f) * 64 + l) * 8) =
        make_uint4(o[0], o[1], o[2], o[3]);
}

// ---------------------------------------------------------------------------
// fused_kernel, 512 threads (8 waves):
//  blk < 128: whole-image block. dots[128][208] = A @ x_b. Per K-step (BK=32):
//    DMA x (26 chunks, 25088B) -> Xf; convert phase Xf->XT bf16[208][40];
//    wave w: 13 MFMA (rows 16w..16w+15 x all cols). A dbuf DMA. vmcnt(0) + 2
//    raw barriers per iter. Register/shuffle softmax epilogue (no big overlay).
//  blk >= 128: pq body, 32 wids per block.
// ---------------------------------------------------------------------------
__global__ __launch_bounds__(512)
void fused_kernel(const float* __restrict__ x,
                  const unsigned short* __restrict__ Afrag,
                  const float* __restrict__ asq_g,
                  float* __restrict__ out0,
                  float* __restrict__ lpart,
                  const float* __restrict__ wlfc,
                  const float* __restrict__ concepts,
                  const float* __restrict__ modulation,
                  float* __restrict__ Rm, float* __restrict__ Qs) {
    __shared__ __align__(16) char smem[61952];
    const int tid = threadIdx.x;
    const int lane = tid & 63;
    const int w = tid >> 6;
    const int blkid = blockIdx.x;

    if (blkid < MAIN_BLKS) {
        const int b = blkid;
        float* Xf = (float*)smem;                              // 25600B (25088 used)
        char* Ab0 = smem + 25600;                              // 2 x 8192
        unsigned short* XT = (unsigned short*)(smem + 41984);  // [208][40] u16 = 16640
        float* xsqL = (float*)(smem + 58624);                  // [2][208]
        float* pmw = (float*)smem;                             // epilogue overlay [8][208]
        float* xwL = (float*)(smem + 8192);                    // epilogue overlay [208]

        const int lo = lane & 15, hi = lane >> 4;
        const char* xim = (const char*)x + (size_t)b * IMGB;
        const char* Ag = (const char*)Afrag;

        const bool act = tid < 416;
        const int h = (act && tid >= 208) ? 1 : 0;
        const int cc = act ? (tid - 208 * h) : 0;

        f32x4 acc[13];
#pragma unroll
        for (int ct = 0; ct < 13; ++ct) acc[ct] = (f32x4){0.f, 0.f, 0.f, 0.f};
        float xs = 0.f;

#define ISSUE_X(JJ) do {                                                        \
        const char* sx_ = xim + (size_t)(JJ) * XSTEP;                           \
        gl16(sx_ + (3 * w + 0) * 1024 + lane * 16, smem + (3 * w + 0) * 1024);  \
        gl16(sx_ + (3 * w + 1) * 1024 + lane * 16, smem + (3 * w + 1) * 1024);  \
        gl16(sx_ + (3 * w + 2) * 1024 + lane * 16, smem + (3 * w + 2) * 1024);  \
        if (w < 2) gl4(sx_ + 24576 + w * 256 + lane * 4,                        \
                       smem + 24576 + w * 256);                                 \
    } while (0)

#define ISSUE_A(JJ) do {                                                        \
        gl16(Ag + (size_t)(JJ) * 8192 + w * 1024 + lane * 16,                   \
             Ab0 + ((JJ) & 1) * 8192 + w * 1024);                               \
    } while (0)

#define VM0() do {                                                              \
        asm volatile("s_waitcnt vmcnt(0)" ::: "memory");                        \
        __builtin_amdgcn_sched_barrier(0);                                      \
    } while (0)

#define LBAR() do {                                                             \
        asm volatile("s_waitcnt lgkmcnt(0)" ::: "memory");                      \
        __builtin_amdgcn_s_barrier();                                           \
        __builtin_amdgcn_sched_barrier(0);                                      \
    } while (0)

#define CONVERT() do {                                                          \
        if (act) {                                                              \
            const float* xp_ = Xf + (16 * h) * 196 + cc;                        \
            float v_[16];                                                       \
            _Pragma("unroll")                                                   \
            for (int q_ = 0; q_ < 16; ++q_) v_[q_] = xp_[q_ * 196];             \
            _Pragma("unroll")                                                   \
            for (int q_ = 0; q_ < 16; ++q_) xs += v_[q_] * v_[q_];              \
            unsigned u_[8];                                                     \
            _Pragma("unroll")                                                   \
            for (int p_ = 0; p_ < 8; ++p_)                                      \
                u_[p_] = cvtpk(v_[2 * p_], v_[2 * p_ + 1]);                     \
            unsigned short* xt_ = XT + cc * 40 + h * 16;                        \
            *reinterpret_cast<uint4*>(xt_) = make_uint4(u_[0], u_[1], u_[2], u_[3]); \
            *reinterpret_cast<uint4*>(xt_ + 8) = make_uint4(u_[4], u_[5], u_[6], u_[7]); \
        }                                                                       \
    } while (0)

#define MFMA_STEP(JJ) do {                                                      \
        const char* Ab_ = Ab0 + ((JJ) & 1) * 8192;                              \
        const bf16x8 afr_ = *reinterpret_cast<const bf16x8*>(                   \
            Ab_ + ((w * 64 + lane) << 4));                                      \
        _Pragma("unroll")                                                       \
        for (int ct_ = 0; ct_ < 13; ++ct_) {                                    \
            const bf16x8 bfr_ = *reinterpret_cast<const bf16x8*>(               \
                (const char*)XT + (ct_ * 16 + lo) * 80 + hi * 16);              \
            acc[ct_] = __builtin_amdgcn_mfma_f32_16x16x32_bf16(                 \
                afr_, bfr_, acc[ct_], 0, 0, 0);                                 \
        }                                                                       \
    } while (0)

        ISSUE_X(0); ISSUE_A(0);
#pragma unroll 1
        for (int j = 0; j < 63; ++j) {
            VM0(); LBAR();          // x(j), A(j) landed everywhere; XT free
            CONVERT();              // Xf -> XT
            LBAR();                 // XT visible; Xf free
            ISSUE_X(j + 1);         // in flight during MFMA
            MFMA_STEP(j);
            ISSUE_A(j + 1);
        }
        VM0(); LBAR(); CONVERT(); LBAR(); MFMA_STEP(63);

        // ------------------ epilogue: register softmax ------------------
        __syncthreads();
        if (act) xsqL[h * 208 + cc] = xs;
        if (w == 7 && hi == 0) {
#pragma unroll
            for (int ct = 0; ct < 13; ++ct) xwL[ct * 16 + lo] = acc[ct][1]; // raw row 113
        }
        __syncthreads();

        float xq[13];
#pragma unroll
        for (int ct = 0; ct < 13; ++ct) {
            const int c = ct * 16 + lo;
            xq[ct] = xsqL[c] + xsqL[208 + c];
        }
        float aq[4];
#pragma unroll
        for (int rr = 0; rr < 4; ++rr) aq[rr] = asq_g[16 * w + 4 * hi + rr];
        const bool v4 = (w < 7);

        float mct[13];
#pragma unroll
        for (int ct = 0; ct < 13; ++ct) {
#pragma unroll
            for (int rr = 0; rr < 4; ++rr) {
                const float d2 = aq[rr] + xq[ct] - 2.f * acc[ct][rr];
                acc[ct][rr] = -sqrtf(fmaxf(d2, 0.f));
            }
            float mv = -3.4e38f;
            if (v4) mv = fmaxf(fmaxf(acc[ct][0], acc[ct][1]),
                               fmaxf(acc[ct][2], acc[ct][3]));
            else if (hi == 0) mv = acc[ct][0];          // row 112 only
            mv = fmaxf(mv, __shfl_xor(mv, 16));
            mv = fmaxf(mv, __shfl_xor(mv, 32));
            mct[ct] = mv;
        }
        if (hi == 0) {
#pragma unroll
            for (int ct = 0; ct < 13; ++ct) pmw[w * 208 + ct * 16 + lo] = mct[ct];
        }
        __syncthreads();
        float Mct[13];
#pragma unroll
        for (int ct = 0; ct < 13; ++ct) {
            float mm = -3.4e38f;
#pragma unroll
            for (int ww = 0; ww < 8; ++ww)
                mm = fmaxf(mm, pmw[ww * 208 + ct * 16 + lo]);
            Mct[ct] = mm;
        }
        __syncthreads();                 // all reads done before pmw reuse
        float sct[13];
#pragma unroll
        for (int ct = 0; ct < 13; ++ct) {
            float ss = 0.f;
#pragma unroll
            for (int rr = 0; rr < 4; ++rr) {
                const bool valid = v4 || (hi == 0 && rr == 0);
                const float e = valid ? __expf(acc[ct][rr] - Mct[ct]) : 0.f;
                acc[ct][rr] = e;
                ss += e;
            }
            ss += __shfl_xor(ss, 16);
            ss += __shfl_xor(ss, 32);
            sct[ct] = ss;
        }
        if (hi == 0) {
#pragma unroll
            for (int ct = 0; ct < 13; ++ct) pmw[w * 208 + ct * 16 + lo] = sct[ct];
        }
        __syncthreads();
        float inv[13];
#pragma unroll
        for (int ct = 0; ct < 13; ++ct) {
            float SS = 0.f;
#pragma unroll
            for (int ww = 0; ww < 8; ++ww) SS += pmw[ww * 208 + ct * 16 + lo];
            inv[ct] = 1.f / SS;
        }

        float* o0 = out0 + (size_t)b * KB * N;
#pragma unroll
        for (int ct = 0; ct < 13; ++ct) {
            const int c = ct * 16 + lo;
            const bool cv = c < N;
#pragma unroll
            for (int rr = 0; rr < 4; ++rr) {
                const int r = 16 * w + 4 * hi + rr;
                const bool valid = v4 || (hi == 0 && rr == 0);
                if (valid && cv) o0[(size_t)r * N + c] = acc[ct][rr] * inv[ct];
            }
        }
        if (v4) {
#pragma unroll
            for (int rr = 0; rr < 4; ++rr) {
                float pv = 0.f;
#pragma unroll
                for (int ct = 0; ct < 13; ++ct) {
                    const int c = ct * 16 + lo;
                    const float term = acc[ct][rr] * inv[ct] * xwL[c];
                    pv += (c < N) ? term : 0.f;   // select (no NaN propagation)
                }
                pv += __shfl_xor(pv, 1);
                pv += __shfl_xor(pv, 2);
                pv += __shfl_xor(pv, 4);
                pv += __shfl_xor(pv, 8);
                if (lo == 0) lpart[(size_t)b * K + 16 * w + 4 * hi + rr] = pv;
            }
        }
    } else {
        // ---------------- pq body: 32 wids per block (4 per wave) -----------
        const int wb = (blkid - MAIN_BLKS) * 32 + w * 4;
#pragma unroll
        for (int q = 0; q < 4; ++q) {
            const int wid = wb + q;
            const int o = wid / K;
            const int k = wid % K;
            const float4* wp = reinterpret_cast<const float4*>(wlfc + (size_t)o * CKC + (size_t)k * C);
            const float4* cp = reinterpret_cast<const float4*>(concepts + (size_t)k * C);
            const float4* mp = reinterpret_cast<const float4*>(modulation);
            float s1 = 0.f, s2 = 0.f;
#pragma unroll
            for (int it = 0; it < 8; ++it) {
                const int idx = it * 64 + lane;
                const float4 w4 = wp[idx];
                const float4 c4 = cp[idx];
                const float4 m4 = mp[idx];
                s1 += w4.x * c4.x + w4.y * c4.y + w4.z * c4.z + w4.w * c4.w;
                s2 += w4.x * m4.x + w4.y * m4.y + w4.z * m4.z + w4.w * m4.w;
            }
            for (int off = 32; off; off >>= 1) {
                s1 += __shfl_down(s1, off);
                s2 += __shfl_down(s2, off);
            }
            if (lane == 0) { Rm[wid] = s1 - s2; Qs[wid] = s2; }
        }
    }
}

// ---------------------------------------------------------------------------
__global__ __launch_bounds__(256)
void final_kernel(const float* __restrict__ lpart, const float* __restrict__ bcfc,
                  const float* __restrict__ Rm, const float* __restrict__ Qs,
                  const float* __restrict__ blfc,
                  float* __restrict__ out1, float* __restrict__ out2) {
    const int b = blockIdx.x;
    const int tid = threadIdx.x;
    __shared__ float g_s[K];
    if (tid < K) {
        const float v = lpart[(size_t)b * K + tid] + bcfc[0];
        const float g = 1.f / (1.f + __expf(-v));
        out1[b * K + tid] = g;
        g_s[tid] = g;
    }
    __syncthreads();
    if (tid < NCLS) {
        float acc = blfc[tid];
        const float* rp = Rm + (size_t)tid * K;
        const float* qp = Qs + (size_t)tid * K;
        for (int k = 0; k < K; ++k) acc = fmaf(g_s[k], rp[k], acc) + qp[k];
        out2[b * NCLS + tid] = acc;
    }
}

extern "C" void kernel_launch(void* const* d_in, const int* in_sizes, int n_in,
                              void* d_out, int out_size, void* d_ws, size_t ws_size,
                              hipStream_t stream) {
    const float* x          = (const float*)d_in[0];
    const float* concepts   = (const float*)d_in[1];
    const float* modulation = (const float*)d_in[2];
    const float* background = (const float*)d_in[3];
    const float* wcfc       = (const float*)d_in[4];
    const float* bcfc       = (const float*)d_in[5];
    const float* wlfc       = (const float*)d_in[6];
    const float* blfc       = (const float*)d_in[7];

    float* out  = (float*)d_out;
    float* out0 = out;
    float* out1 = out + OUT1_OFF;
    float* out2 = out + OUT2_OFF;

    float* ws    = (float*)d_ws;
    float* asq   = ws;                               // 128
    float* lpart = asq + MROWS;                      // B*K = 14336
    float* Rm    = lpart + (size_t)B * K;            // 22400
    float* Qs    = Rm + NCLS * K;                    // 22400
    unsigned short* Afrag = (unsigned short*)(Qs + NCLS * K);  // 512KB

    asq_kernel<<<MROWS, 256, 0, stream>>>(concepts, background, wcfc, asq);
    pack_kernel<<<dim3(8, 64), 64, 0, stream>>>(concepts, background, wcfc, Afrag);
    fused_kernel<<<MAIN_BLKS + PQ_BLKS, 512, 0, stream>>>(
        x, Afrag, asq, out0, lpart, wlfc, concepts, modulation, Rm, Qs);
    final_kernel<<<B, 256, 0, stream>>>(lpart, bcfc, Rm, Qs, blfc, out1, out2);
}